// Round 1
// 1755.264 us; speedup vs baseline: 1.3920x; 1.3920x over previous
//
#include <hip/hip_runtime.h>
#include <hip/hip_fp16.h>

#define BATCH 256
#define SEQ   2048
#define ISZ   64
#define HID   128
#define GATES 512   // 4*HID
#define KV    192   // ISZ + HID
#define KSL   96    // k-slice per lane (KV/2)
#define KSH   48    // half2 per k-slice

typedef _Float16 half2v __attribute__((ext_vector_type(2)));

#if __has_builtin(__builtin_amdgcn_fdot2)
#define FDOT2(a, b, c) __builtin_amdgcn_fdot2((a), (b), (c), false)
#else
static __device__ __forceinline__ float fdot2_fb(half2v a, half2v b, float c) {
    c = fmaf((float)a[0], (float)b[0], c);
    c = fmaf((float)a[1], (float)b[1], c);
    return c;
}
#define FDOT2(a, b, c) fdot2_fb((a), (b), (c))
#endif

// One block per batch element, 256 threads (4 waves, 1 wave/SIMD).
// Lane layout: p = lane>>5 selects k-half [p*96, p*96+96) of v=[x|h] (f16).
//              j = wave*32 + (lane&31) is the hidden unit this lane owns.
// Each lane computes 4 columns {j, 128+j, 256+j, 384+j} -- one per gate
// type (i,f,o,z) -- over its k-half. A single __shfl_xor(.,32) completes
// each dot product, so gate transform AND the stabilized state update run
// entirely in-lane (replicated in both k-halves; lanes<32 write results).
// vh is double-buffered => exactly ONE __syncthreads() per timestep.
__global__ __launch_bounds__(256, 1) void slstm_kernel(
    const float* __restrict__ x, const float* __restrict__ W,
    const float* __restrict__ R, const float* __restrict__ bias,
    float* __restrict__ out)
{
    __shared__ __align__(16) __half vh[2][KV];   // ping-pong [x_t | h] in f16

    const int t    = threadIdx.x;
    const int lane = t & 63;
    const int w    = t >> 6;          // 0..3
    const int jj   = lane & 31;
    const int j    = w * 32 + jj;     // hidden unit 0..127
    const int p    = lane >> 5;       // k-part 0/1

    // ---- preload weights: col i*128+j, k = p*96+kk, packed half2 ----
    half2v wh[4][KSH];
#pragma unroll
    for (int i = 0; i < 4; ++i) {
        const int c = i * HID + j;
#pragma unroll
        for (int kk = 0; kk < KSL; kk += 2) {
            const int k0 = p * KSL + kk;   // even; W/R split at 64 never splits a pair
            const int k1 = k0 + 1;
            const float f0 = (k0 < ISZ) ? W[c * ISZ + k0] : R[(k0 - ISZ) * GATES + c];
            const float f1 = (k1 < ISZ) ? W[c * ISZ + k1] : R[(k1 - ISZ) * GATES + c];
            half2v hv;
            hv[0] = (_Float16)f0;
            hv[1] = (_Float16)f1;
            wh[i][kk / 2] = hv;
        }
    }

    float bb[4];
#pragma unroll
    for (int i = 0; i < 4; ++i) bb[i] = bias[i * HID + j];

    float c_st = 0.f, n_st = 0.f, m_st = 0.f;

    const float* xb   = x   + (size_t)blockIdx.x * SEQ * ISZ;
    float*       outb = out + (size_t)blockIdx.x * SEQ * HID;

    // init buffer 0: h = 0, x_0; prefetch x_1
    if (lane < 32) vh[0][ISZ + j] = __half(0.0f);
    float xreg = 0.f;
    if (t < ISZ) {
        vh[0][t] = __half(xb[t]);
        xreg = xb[ISZ + t];
    }
    __syncthreads();

    for (int s = 0; s < SEQ; ++s) {
        const __half* vcur = vh[s & 1];
        __half*       vnxt = vh[(s + 1) & 1];

        // ---- read this lane's 96-half slice (192 B) as 12 x uint4 ----
        // addresses hit 4 disjoint bank quads broadcast to 32 lanes: conflict-free
        const uint4* vp = (const uint4*)((const char*)vcur + p * (KSL * 2));
        uint4 cq[12];
#pragma unroll
        for (int i = 0; i < 12; ++i) cq[i] = vp[i];

        // ---- 192 x v_dot2_f32_f16: 4 gate columns x 48 half2 ----
        float acc0 = 0.f, acc1 = 0.f, acc2 = 0.f, acc3 = 0.f;
#pragma unroll
        for (int i = 0; i < 12; ++i) {
            const uint32_t u0 = cq[i].x, u1 = cq[i].y, u2 = cq[i].z, u3 = cq[i].w;
            const half2v h0 = __builtin_bit_cast(half2v, u0);
            const half2v h1 = __builtin_bit_cast(half2v, u1);
            const half2v h2 = __builtin_bit_cast(half2v, u2);
            const half2v h3 = __builtin_bit_cast(half2v, u3);
            acc0 = FDOT2(h0, wh[0][i * 4 + 0], acc0);
            acc1 = FDOT2(h0, wh[1][i * 4 + 0], acc1);
            acc2 = FDOT2(h0, wh[2][i * 4 + 0], acc2);
            acc3 = FDOT2(h0, wh[3][i * 4 + 0], acc3);
            acc0 = FDOT2(h1, wh[0][i * 4 + 1], acc0);
            acc1 = FDOT2(h1, wh[1][i * 4 + 1], acc1);
            acc2 = FDOT2(h1, wh[2][i * 4 + 1], acc2);
            acc3 = FDOT2(h1, wh[3][i * 4 + 1], acc3);
            acc0 = FDOT2(h2, wh[0][i * 4 + 2], acc0);
            acc1 = FDOT2(h2, wh[1][i * 4 + 2], acc1);
            acc2 = FDOT2(h2, wh[2][i * 4 + 2], acc2);
            acc3 = FDOT2(h2, wh[3][i * 4 + 2], acc3);
            acc0 = FDOT2(h3, wh[0][i * 4 + 3], acc0);
            acc1 = FDOT2(h3, wh[1][i * 4 + 3], acc1);
            acc2 = FDOT2(h3, wh[2][i * 4 + 3], acc2);
            acc3 = FDOT2(h3, wh[3][i * 4 + 3], acc3);
        }

        // ---- complete dot products across k-halves (lane xor 32) ----
        acc0 += __shfl_xor(acc0, 32);
        acc1 += __shfl_xor(acc1, 32);
        acc2 += __shfl_xor(acc2, 32);
        acc3 += __shfl_xor(acc3, 32);

        const float gi = acc0 + bb[0];
        const float gf = acc1 + bb[1];
        const float go = acc2 + bb[2];
        const float gz = acc3 + bb[3];

        // ---- gate transforms (in-lane; acc index == gate type) ----
        const float yf = -gf;                                   // f: log_sigmoid
        const float sp = (yf > 15.f) ? yf : __logf(1.f + __expf(yf));
        const float lf = -sp;
        const float so = __builtin_amdgcn_rcpf(1.f + __expf(-go));  // o: sigmoid
        const float ez = __expf(2.f * gz);                          // z: tanh
        const float tz = 1.f - 2.f * __builtin_amdgcn_rcpf(ez + 1.f);

        // ---- stabilized state update (replicated in both lane halves) ----
        const float m_new = fmaxf(lf + m_st, gi);
        const float ip    = __expf(gi - m_new);
        const float fp    = __expf(lf + m_st - m_new);
        c_st = fp * c_st + ip * tz;
        n_st = fp * n_st + ip;
        m_st = m_new;

        const float ratio = c_st * __builtin_amdgcn_rcpf(n_st);
        const float eh    = __expf(2.f * ratio);
        const float h     = so * (1.f - 2.f * __builtin_amdgcn_rcpf(eh + 1.f));

        // ---- publish h (next buffer) + coalesced f32 output store ----
        if (lane < 32) {
            vnxt[ISZ + j]     = __half(h);
            outb[s * HID + j] = h;
        }
        // ---- publish x_{s+1} into next buffer, prefetch x_{s+2} (wave 0) ----
        if (t < ISZ) {
            vnxt[t] = __half(xreg);
            xreg    = (s + 2 < SEQ) ? xb[(s + 2) * ISZ + t] : 0.f;
        }
        __syncthreads();   // single barrier: next step reads vnxt
    }
}

extern "C" void kernel_launch(void* const* d_in, const int* in_sizes, int n_in,
                              void* d_out, int out_size, void* d_ws, size_t ws_size,
                              hipStream_t stream) {
    const float* x = (const float*)d_in[0];
    const float* W = (const float*)d_in[1];
    const float* R = (const float*)d_in[2];
    const float* b = (const float*)d_in[3];
    float* out = (float*)d_out;

    slstm_kernel<<<dim3(BATCH), dim3(256), 0, stream>>>(x, W, R, b, out);
}

// Round 2
// 1671.599 us; speedup vs baseline: 1.4617x; 1.0501x over previous
//
#include <hip/hip_runtime.h>
#include <hip/hip_fp16.h>

#define BATCH 256
#define SEQ   2048
#define ISZ   64
#define HID   128
#define GATES 512   // 4*HID
#define KV    192   // ISZ + HID
#define NP    4     // k-parts per hidden unit
#define KSL   48    // KV / NP (k elements per lane)
#define KSH   24    // half2 per k-slice

typedef _Float16 half2v __attribute__((ext_vector_type(2)));

#if __has_builtin(__builtin_amdgcn_fdot2)
#define FDOT2(a, b, c) __builtin_amdgcn_fdot2((a), (b), (c), false)
#else
static __device__ __forceinline__ float fdot2_fb(half2v a, half2v b, float c) {
    c = fmaf((float)a[0], (float)b[0], c);
    c = fmaf((float)a[1], (float)b[1], c);
    return c;
}
#define FDOT2(a, b, c) fdot2_fb((a), (b), (c))
#endif

// In-quad butterfly add via DPP quad_perm (pure VALU, no LDS pipe).
// xor1: perm [1,0,3,2] = 0xB1 ; xor2: perm [2,3,0,1] = 0x4E
#if __has_builtin(__builtin_amdgcn_update_dpp)
template <int CTRL>
static __device__ __forceinline__ float qadd(float v) {
    const int y = __builtin_amdgcn_update_dpp(
        0, __builtin_bit_cast(int, v), CTRL, 0xF, 0xF, true);
    return v + __builtin_bit_cast(float, y);
}
#define QRED(a) do { a = qadd<0xB1>(a); a = qadd<0x4E>(a); } while (0)
#else
#define QRED(a) do { a += __shfl_xor(a, 1); a += __shfl_xor(a, 2); } while (0)
#endif

// One block per batch element, 512 threads (8 waves = 2 waves/SIMD).
// Lane layout: j = wave*16 + (lane>>2) is the hidden unit (0..127);
//              p = lane&3 selects k-slice [p*48, p*48+48) of v=[x|h] (f16).
// Each lane computes 4 gate columns {j, 128+j, 256+j, 384+j} over its
// k-slice (96 x v_dot2). Quad reduction (xor1+xor2) is done with DPP
// quad_perm adds -- no LDS traffic. Gate transforms + state update run
// in-lane, replicated across the quad; p==0 lanes publish h.
// State is kept UNstabilized (C = c*e^m, N = n*e^m) -- mathematically
// identical to the stabilized reference, |C/N| <= 1, all magnitudes
// bounded by ~e^15 so f32-safe; removes log1p + 2 exp from the chain.
// vh is double-buffered => ONE __syncthreads() per timestep.
__global__ __launch_bounds__(512, 2) void slstm_kernel(
    const float* __restrict__ x, const float* __restrict__ W,
    const float* __restrict__ R, const float* __restrict__ bias,
    float* __restrict__ out)
{
    __shared__ __align__(16) __half vh[2][KV];   // ping-pong [x_t | h] in f16

    const int t    = threadIdx.x;
    const int lane = t & 63;
    const int w    = t >> 6;            // 0..7
    const int j    = w * 16 + (lane >> 2);   // hidden unit 0..127
    const int p    = lane & 3;               // k-part 0..3

    // ---- preload weights: col i*128+j, k = p*48+kk, packed half2 ----
    half2v wh[4][KSH];
#pragma unroll
    for (int i = 0; i < 4; ++i) {
        const int c = i * HID + j;
#pragma unroll
        for (int kk = 0; kk < KSL; kk += 2) {
            const int k0 = p * KSL + kk;   // even; W/R split at 64 never splits a pair
            const int k1 = k0 + 1;
            const float f0 = (k0 < ISZ) ? W[c * ISZ + k0] : R[(k0 - ISZ) * GATES + c];
            const float f1 = (k1 < ISZ) ? W[c * ISZ + k1] : R[(k1 - ISZ) * GATES + c];
            half2v hv;
            hv[0] = (_Float16)f0;
            hv[1] = (_Float16)f1;
            wh[i][kk / 2] = hv;
        }
    }

    float bb[4];
#pragma unroll
    for (int i = 0; i < 4; ++i) bb[i] = bias[i * HID + j];

    float C_st = 0.f, N_st = 0.f;

    const float* xb   = x   + (size_t)blockIdx.x * SEQ * ISZ;
    float*       outb = out + (size_t)blockIdx.x * SEQ * HID;

    // init buffer 0: h = 0, x_0; prefetch x_1 (wave 0 handles x duty)
    if (t < HID) vh[0][ISZ + t] = __half(0.0f);
    float xreg = 0.f;
    if (t < ISZ) {
        vh[0][t] = __half(xb[t]);
        xreg = xb[ISZ + t];
    }
    __syncthreads();

    for (int s = 0; s < SEQ; ++s) {
        const __half* vcur = vh[s & 1];
        __half*       vnxt = vh[(s + 1) & 1];

        // ---- read this lane's 48-half slice (96 B) as 6 x uint4 ----
        // quad p=0..3 hits banks {4i..}, {24+4i..}, {16+4i..}, {8+4i..}:
        // disjoint -> conflict-free; 16-lane broadcast per address.
        const uint4* vp = (const uint4*)((const char*)vcur + p * (KSL * 2));
        uint4 cq[6];
#pragma unroll
        for (int i = 0; i < 6; ++i) cq[i] = vp[i];

        // ---- 96 x v_dot2_f32_f16: 4 gate columns x 24 half2 ----
        float a0 = 0.f, a1 = 0.f, a2 = 0.f, a3 = 0.f;
#pragma unroll
        for (int i = 0; i < 6; ++i) {
            const half2v h0 = __builtin_bit_cast(half2v, cq[i].x);
            const half2v h1 = __builtin_bit_cast(half2v, cq[i].y);
            const half2v h2 = __builtin_bit_cast(half2v, cq[i].z);
            const half2v h3 = __builtin_bit_cast(half2v, cq[i].w);
            a0 = FDOT2(h0, wh[0][i * 4 + 0], a0);
            a1 = FDOT2(h0, wh[1][i * 4 + 0], a1);
            a2 = FDOT2(h0, wh[2][i * 4 + 0], a2);
            a3 = FDOT2(h0, wh[3][i * 4 + 0], a3);
            a0 = FDOT2(h1, wh[0][i * 4 + 1], a0);
            a1 = FDOT2(h1, wh[1][i * 4 + 1], a1);
            a2 = FDOT2(h1, wh[2][i * 4 + 1], a2);
            a3 = FDOT2(h1, wh[3][i * 4 + 1], a3);
            a0 = FDOT2(h2, wh[0][i * 4 + 2], a0);
            a1 = FDOT2(h2, wh[1][i * 4 + 2], a1);
            a2 = FDOT2(h2, wh[2][i * 4 + 2], a2);
            a3 = FDOT2(h2, wh[3][i * 4 + 2], a3);
            a0 = FDOT2(h3, wh[0][i * 4 + 3], a0);
            a1 = FDOT2(h3, wh[1][i * 4 + 3], a1);
            a2 = FDOT2(h3, wh[2][i * 4 + 3], a2);
            a3 = FDOT2(h3, wh[3][i * 4 + 3], a3);
        }

        // ---- complete dot products across the quad (pure VALU DPP) ----
        QRED(a0);
        QRED(a1);
        QRED(a2);
        QRED(a3);

        const float gi = a0 + bb[0];
        const float gf = a1 + bb[1];
        const float go = a2 + bb[2];
        const float gz = a3 + bb[3];

        // ---- gate transforms + unstabilized state update (in-lane) ----
        const float fp = __builtin_amdgcn_rcpf(1.f + __expf(-gf));  // sigmoid(f)
        const float ip = __expf(gi);                                 // exp(i)
        const float ez = __expf(2.f * gz);                           // tanh(z)
        const float tz = 1.f - 2.f * __builtin_amdgcn_rcpf(ez + 1.f);
        const float so = __builtin_amdgcn_rcpf(1.f + __expf(-go));  // sigmoid(o)

        C_st = fp * C_st + ip * tz;
        N_st = fp * N_st + ip;

        const float ratio = C_st * __builtin_amdgcn_rcpf(N_st);      // |ratio| <= 1
        const float eh    = __expf(2.f * ratio);
        const float h     = so * (1.f - 2.f * __builtin_amdgcn_rcpf(eh + 1.f));

        // ---- publish h (next buffer) + coalesced f32 output store ----
        if (p == 0) {
            vnxt[ISZ + j]     = __half(h);
            outb[s * HID + j] = h;
        }
        // ---- publish x_{s+1} into next buffer, prefetch x_{s+2} ----
        if (t < ISZ) {
            vnxt[t] = __half(xreg);
            xreg    = (s + 2 < SEQ) ? xb[(s + 2) * ISZ + t] : 0.f;
        }
        __syncthreads();   // single barrier: next step reads vnxt
    }
}

extern "C" void kernel_launch(void* const* d_in, const int* in_sizes, int n_in,
                              void* d_out, int out_size, void* d_ws, size_t ws_size,
                              hipStream_t stream) {
    const float* x = (const float*)d_in[0];
    const float* W = (const float*)d_in[1];
    const float* R = (const float*)d_in[2];
    const float* b = (const float*)d_in[3];
    float* out = (float*)d_out;

    slstm_kernel<<<dim3(BATCH), dim3(512), 0, stream>>>(x, W, R, b, out);
}

// Round 3
// 1555.886 us; speedup vs baseline: 1.5704x; 1.0744x over previous
//
#include <hip/hip_runtime.h>
#include <hip/hip_fp16.h>

#define BATCH 256
#define SEQ   2048
#define ISZ   64
#define HID   128
#define GATES 512   // 4*HID
#define KV    192   // ISZ + HID
#define NT    4     // N-tiles (of 16) per wave
#define KT    6     // K-tiles (of 32)

typedef _Float16 f16x8 __attribute__((ext_vector_type(8)));
typedef float    f32x4 __attribute__((ext_vector_type(4)));

// One block per batch element, 512 threads (8 waves = 2 waves/SIMD).
// The per-step gate GEMV (1x192)@(192x512) runs on the MATRIX pipe:
// v_mfma_f32_16x16x32_f16, wave w owns N-slice [w*64, w*64+64) =
// 4 N-tiles x 6 K-tiles = 24 MFMA/wave/step. The 1-row A operand is
// BROADCAST into all 16 M-rows (all lanes read the same 16B from LDS):
//  - A row-mapping becomes irrelevant (all rows identical),
//  - any consistent k-slot permutation cancels between A and B,
//  - every C row equals the true gate row, so extraction only relies on
//    the verified C mapping col = lane&15.
// Weights live permanently in VGPRs as B-fragments (96 VGPR/lane).
// Pointwise: waves 0-3 (one per SIMD), lanes 0-31, one hidden unit each
// (unstabilized C,N recurrence == stabilized reference algebraically).
// vh ping-pong; two barriers/step (gates->pointwise, h->next A-read).
__global__ __launch_bounds__(512, 2) void slstm_kernel(
    const float* __restrict__ x, const float* __restrict__ W,
    const float* __restrict__ R, const float* __restrict__ bias,
    float* __restrict__ out)
{
    __shared__ __align__(16) _Float16 vh[2][KV];   // ping-pong [x_t | h] f16
    __shared__ __align__(16) float    gv[GATES];   // raw gates (pre-bias)

    const int t    = threadIdx.x;
    const int lane = t & 63;
    const int w    = t >> 6;        // 0..7
    const int col  = lane & 15;     // MFMA N-col / C-col
    const int g    = lane >> 4;     // k-group 0..3

    // ---- preload B-fragments: tile (nt,kt), n = w*64+nt*16+col,
    //      k = kt*32 + g*8 + e  (same slot rule as A-frags) ----
    f16x8 bw[NT][KT];
#pragma unroll
    for (int nt = 0; nt < NT; ++nt) {
        const int n = w * 64 + nt * 16 + col;
#pragma unroll
        for (int kt = 0; kt < KT; ++kt) {
            f16x8 v;
#pragma unroll
            for (int e = 0; e < 8; ++e) {
                const int k = kt * 32 + g * 8 + e;
                const float f = (k < ISZ) ? W[n * ISZ + k]
                                          : R[(k - ISZ) * GATES + n];
                v[e] = (_Float16)f;
            }
            bw[nt][kt] = v;
        }
    }

    // ---- pointwise ownership: waves 0-3, lanes 0-31 -> unit j ----
    const bool owner = (w < 4) && (lane < 32);
    const int  j     = (w & 3) * 32 + (lane & 31);
    float bb0 = 0.f, bb1 = 0.f, bb2 = 0.f, bb3 = 0.f;
    if (owner) {
        bb0 = bias[j];
        bb1 = bias[HID + j];
        bb2 = bias[2 * HID + j];
        bb3 = bias[3 * HID + j];
    }
    float C_st = 0.f, N_st = 0.f;

    const float* xb   = x   + (size_t)blockIdx.x * SEQ * ISZ;
    float*       outb = out + (size_t)blockIdx.x * SEQ * HID;

    // init buffer 0: h = 0, x_0; prefetch x_1
    if (t < HID) vh[0][ISZ + t] = (_Float16)0.f;
    float xreg = 0.f;
    if (t < ISZ) {
        vh[0][t] = (_Float16)xb[t];
        xreg = xb[ISZ + t];
    }
    __syncthreads();

    for (int s = 0; s < SEQ; ++s) {
        const _Float16* vcur = vh[s & 1];
        _Float16*       vnxt = vh[(s + 1) & 1];

        // ---- A-fragments: broadcast v-slice into all 16 rows ----
        // af[kt] = v[kt*32 + g*8 .. +8); 4 distinct addrs -> conflict-free
        const f16x8* va = (const f16x8*)vcur;
        f16x8 af[KT];
#pragma unroll
        for (int kt = 0; kt < KT; ++kt) af[kt] = va[kt * 4 + g];

        // ---- 24 MFMA: acc[nt] += af[kt] * bw[nt][kt] ----
        f32x4 acc[NT];
#pragma unroll
        for (int nt = 0; nt < NT; ++nt) {
            f32x4 a = {0.f, 0.f, 0.f, 0.f};
#pragma unroll
            for (int kt = 0; kt < KT; ++kt)
                a = __builtin_amdgcn_mfma_f32_16x16x32_f16(af[kt], bw[nt][kt], a, 0, 0, 0);
            acc[nt] = a;
        }

        // ---- extract gates: every C row is the true row; col = lane&15 ----
        if (lane < 16) {
#pragma unroll
            for (int nt = 0; nt < NT; ++nt)
                gv[w * 64 + nt * 16 + lane] = acc[nt][0];
        }
        __syncthreads();   // gates visible

        // ---- publish x_{s+1} early (wave 0), prefetch x_{s+2} ----
        if (t < ISZ) {
            vnxt[t] = (_Float16)xreg;
            xreg    = (s + 2 < SEQ) ? xb[(s + 2) * ISZ + t] : 0.f;
        }

        // ---- pointwise state update (1 unit/lane, 1 wave/SIMD) ----
        if (owner) {
            const float gi = gv[j]           + bb0;
            const float gf = gv[HID + j]     + bb1;
            const float go = gv[2 * HID + j] + bb2;
            const float gz = gv[3 * HID + j] + bb3;

            const float fp = __builtin_amdgcn_rcpf(1.f + __expf(-gf)); // sigmoid(f)
            const float ip = __expf(gi);                                // exp(i)
            const float ez = __expf(2.f * gz);                          // tanh(z)
            const float tz = 1.f - 2.f * __builtin_amdgcn_rcpf(ez + 1.f);
            const float so = __builtin_amdgcn_rcpf(1.f + __expf(-go)); // sigmoid(o)

            C_st = fp * C_st + ip * tz;
            N_st = fp * N_st + ip;

            const float ratio = C_st * __builtin_amdgcn_rcpf(N_st);    // |ratio| <= 1
            const float eh    = __expf(2.f * ratio);
            const float h     = so * (1.f - 2.f * __builtin_amdgcn_rcpf(eh + 1.f));

            vnxt[ISZ + j]     = (_Float16)h;   // feed next step
            outb[s * HID + j] = h;             // coalesced f32 store
        }
        __syncthreads();   // vnxt complete before next A-read
    }
}

extern "C" void kernel_launch(void* const* d_in, const int* in_sizes, int n_in,
                              void* d_out, int out_size, void* d_ws, size_t ws_size,
                              hipStream_t stream) {
    const float* x = (const float*)d_in[0];
    const float* W = (const float*)d_in[1];
    const float* R = (const float*)d_in[2];
    const float* b = (const float*)d_in[3];
    float* out = (float*)d_out;

    slstm_kernel<<<dim3(BATCH), dim3(512), 0, stream>>>(x, W, R, b, out);
}

// Round 4
// 1414.982 us; speedup vs baseline: 1.7268x; 1.0996x over previous
//
#include <hip/hip_runtime.h>
#include <hip/hip_fp16.h>

#define BATCH 256
#define SEQ   2048
#define ISZ   64
#define HID   128
#define GATES 512   // 4*HID
#define KV    192   // ISZ + HID
#define KT    6     // K-tiles (of 32)

typedef _Float16 f16x8 __attribute__((ext_vector_type(8)));
typedef float    f32x4 __attribute__((ext_vector_type(4)));

// One block per batch element, 512 threads (8 waves = 2 waves/SIMD).
// Gate GEMV (1x192)@(192x512) on the matrix pipe, but with GATE-QUAD
// ownership: wave w owns hidden units [w*16, w*16+16); its 4 N-tiles are
// the 4 gate types for those units (columns q*128 + w*16 + c).  After the
// MFMA, lane c holds (i,f,o,z) for unit j = w*16+c IN-REGISTER (A is
// broadcast into all 16 M-rows, so every C row is the true gate row;
// verified C mapping col = lane&15).  Pointwise + state update run
// in-wave with no LDS round-trip => ONE barrier per step.
// MFMA loop is kt-outer / q-inner: adjacent MFMAs hit different
// accumulators (4 independent chains/wave, 8/SIMD) -- no dependency
// stalls (round-3's nt-outer ordering serialized 6-deep chains and
// showed as MfmaUtil 49% pure latency).
// Weights live permanently in VGPRs as B-fragments (96 VGPR/lane).
// State is unstabilized (C = c*e^m, N = n*e^m): algebraically identical
// to the stabilized reference, |C/N| <= 1, f32-safe.
__global__ __launch_bounds__(512, 2) void slstm_kernel(
    const float* __restrict__ x, const float* __restrict__ W,
    const float* __restrict__ R, const float* __restrict__ bias,
    float* __restrict__ out)
{
    __shared__ __align__(16) _Float16 vh[2][KV];   // ping-pong [x_t | h] f16

    const int t    = threadIdx.x;
    const int lane = t & 63;
    const int w    = t >> 6;        // 0..7
    const int c16  = lane & 15;     // MFMA N-col / C-col
    const int g    = lane >> 4;     // k-group 0..3
    const int j    = w * 16 + c16;  // hidden unit this lane carries

    // ---- preload B-fragments: gate q, unit j -> column n = q*128 + j,
    //      k = kt*32 + g*8 + e (same slot rule as A-frags; any consistent
    //      k-permutation cancels between A and B) ----
    f16x8 bw[4][KT];
#pragma unroll
    for (int q = 0; q < 4; ++q) {
        const int n = q * HID + j;
#pragma unroll
        for (int kt = 0; kt < KT; ++kt) {
            f16x8 v;
#pragma unroll
            for (int e = 0; e < 8; ++e) {
                const int k = kt * 32 + g * 8 + e;
                const float f = (k < ISZ) ? W[n * ISZ + k]
                                          : R[(k - ISZ) * GATES + n];
                v[e] = (_Float16)f;
            }
            bw[q][kt] = v;
        }
    }

    float bb[4];
#pragma unroll
    for (int q = 0; q < 4; ++q) bb[q] = bias[q * HID + j];

    float C_st = 0.f, N_st = 0.f;   // replicated across the 4 row-groups

    const float* xb   = x   + (size_t)blockIdx.x * SEQ * ISZ;
    float*       outb = out + (size_t)blockIdx.x * SEQ * HID;

    // init buffer 0: h = 0, x_0; prefetch x_1
    if (t < HID) vh[0][ISZ + t] = (_Float16)0.f;
    float xreg = 0.f;
    if (t < ISZ) {
        vh[0][t] = (_Float16)xb[t];
        xreg = xb[ISZ + t];
    }
    __syncthreads();

    for (int s = 0; s < SEQ; ++s) {
        const _Float16* vcur = vh[s & 1];
        _Float16*       vnxt = vh[(s + 1) & 1];

        // ---- A-fragments: broadcast v-slice into all 16 rows ----
        // af[kt] = v[kt*32 + g*8 .. +8); 4 distinct addrs -> conflict-free
        const f16x8* va = (const f16x8*)vcur;
        f16x8 af[KT];
#pragma unroll
        for (int kt = 0; kt < KT; ++kt) af[kt] = va[kt * 4 + g];

        // ---- 24 MFMA, kt-outer / q-inner: 4 independent acc chains ----
        f32x4 acc[4] = {{0.f,0.f,0.f,0.f}, {0.f,0.f,0.f,0.f},
                        {0.f,0.f,0.f,0.f}, {0.f,0.f,0.f,0.f}};
#pragma unroll
        for (int kt = 0; kt < KT; ++kt) {
#pragma unroll
            for (int q = 0; q < 4; ++q)
                acc[q] = __builtin_amdgcn_mfma_f32_16x16x32_f16(
                    af[kt], bw[q][kt], acc[q], 0, 0, 0);
        }

        // ---- gates for unit j are in-register (every row is true row) ----
        const float gi = acc[0][0] + bb[0];
        const float gf = acc[1][0] + bb[1];
        const float go = acc[2][0] + bb[2];
        const float gz = acc[3][0] + bb[3];

        // ---- pointwise, replicated in all lanes (no divergence) ----
        const float fp = __builtin_amdgcn_rcpf(1.f + __expf(-gf)); // sigmoid(f)
        const float ip = __expf(gi);                                // exp(i)
        const float ez = __expf(2.f * gz);                          // tanh(z)
        const float tz = 1.f - 2.f * __builtin_amdgcn_rcpf(ez + 1.f);
        const float so = __builtin_amdgcn_rcpf(1.f + __expf(-go)); // sigmoid(o)

        C_st = fp * C_st + ip * tz;
        N_st = fp * N_st + ip;

        const float ratio = C_st * __builtin_amdgcn_rcpf(N_st);    // |ratio| <= 1
        const float eh    = __expf(2.f * ratio);
        const float h     = so * (1.f - 2.f * __builtin_amdgcn_rcpf(eh + 1.f));

        // ---- publish h (lanes 0-15 of each wave) + output store ----
        if (lane < 16) {
            vnxt[ISZ + j]     = (_Float16)h;
            outb[s * HID + j] = h;
        }
        // ---- publish x_{s+1} (wave 0), prefetch x_{s+2} ----
        if (t < ISZ) {
            vnxt[t] = (_Float16)xreg;
            xreg    = (s + 2 < SEQ) ? xb[(s + 2) * ISZ + t] : 0.f;
        }
        __syncthreads();   // single barrier: vnxt complete for next step
    }
}

extern "C" void kernel_launch(void* const* d_in, const int* in_sizes, int n_in,
                              void* d_out, int out_size, void* d_ws, size_t ws_size,
                              hipStream_t stream) {
    const float* x = (const float*)d_in[0];
    const float* W = (const float*)d_in[1];
    const float* R = (const float*)d_in[2];
    const float* b = (const float*)d_in[3];
    float* out = (float*)d_out;

    slstm_kernel<<<dim3(BATCH), dim3(512), 0, stream>>>(x, W, R, b, out);
}